// Round 1
// baseline (178.734 us; speedup 1.0000x reference)
//
#include <hip/hip_runtime.h>

// Problem constants (from reference setup_inputs)
constexpr int B = 4;
constexpr int L = 512;
constexpr int C = 128;
constexpr int O = 2;
constexpr int PAIRS = L * (L + 1) / 2;   // 131328 upper-tri pairs (incl. diagonal) per batch
constexpr int WAVES_PER_BLOCK = 4;       // 256 threads

__device__ __forceinline__ int tri_offset(int l) {
    // start index of row l in upper-triangular (l<=m) enumeration
    return l * L - (l * (l - 1)) / 2;
}

__global__ __launch_bounds__(256) void contact_map_kernel(
    const float* __restrict__ feat,   // [B,L,L,C]
    const int*   __restrict__ flag,   // [B,L,L]
    const float* __restrict__ W,      // [C,O]
    const float* __restrict__ bias,   // [O]
    float*       __restrict__ out)    // [B,L,L,O]
{
    const int lane = threadIdx.x & 63;
    const int waveInBlock = threadIdx.x >> 6;
    const long long w = (long long)blockIdx.x * WAVES_PER_BLOCK + waveInBlock;
    if (w >= (long long)B * PAIRS) return;

    const int b = (int)(w / PAIRS);
    const int p = (int)(w % PAIRS);

    // ---- decode (l, m) with l <= m from triangular index p ----
    // offset(l) = l*L - l(l-1)/2 <= p  =>  l = ((2L+1) - sqrt((2L+1)^2 - 8p)) / 2
    float disc = (float)((2 * L + 1) * (2 * L + 1)) - 8.0f * (float)p;
    int l = (int)(((float)(2 * L + 1) - sqrtf(disc)) * 0.5f);
    if (l < 0) l = 0;
    if (l > L - 1) l = L - 1;
    // exact integer fixup (float sqrt may be off by 1 at boundaries)
    while (l + 1 <= L - 1 && tri_offset(l + 1) <= p) ++l;
    while (tri_offset(l) > p) --l;
    const int m = l + (p - tri_offset(l));

    // ---- coalesced loads: each lane owns channels {2*lane, 2*lane+1} ----
    const size_t idxLM = ((size_t)b * L + l) * L + m;
    const size_t idxML = ((size_t)b * L + m) * L + l;
    const float* rowLM = feat + idxLM * C;
    const float* rowML = feat + idxML * C;

    const float2 flm = *(const float2*)(rowLM + lane * 2);
    const float2 fml = *(const float2*)(rowML + lane * 2);
    // W[c][o] at W[c*2+o]; lane needs W[2*lane][0..1] and W[2*lane+1][0..1]
    const float4 w4 = *(const float4*)(W + lane * 4);

    // relu + symmetrize
    const float x0 = 0.5f * (fmaxf(flm.x, 0.0f) + fmaxf(fml.x, 0.0f));
    const float x1 = 0.5f * (fmaxf(flm.y, 0.0f) + fmaxf(fml.y, 0.0f));

    // partial dot products for the 2 outputs
    float s0 = x0 * w4.x + x1 * w4.z;
    float s1 = x0 * w4.y + x1 * w4.w;

    // ---- wave64 butterfly reduction ----
    #pragma unroll
    for (int k = 32; k >= 1; k >>= 1) {
        s0 += __shfl_xor(s0, k, 64);
        s1 += __shfl_xor(s1, k, 64);
    }

    // ---- lane 0 writes both symmetric positions with their masks ----
    if (lane == 0) {
        const float b0 = bias[0];
        const float b1 = bias[1];
        const float2 val = make_float2(s0 + b0, s1 + b1);
        const float2 zero = make_float2(0.0f, 0.0f);

        const float2 o1 = (flag[idxLM] != 0) ? val : zero;
        *(float2*)(out + idxLM * O) = o1;
        if (m != l) {
            const float2 o2 = (flag[idxML] != 0) ? val : zero;
            *(float2*)(out + idxML * O) = o2;
        }
    }
}

extern "C" void kernel_launch(void* const* d_in, const int* in_sizes, int n_in,
                              void* d_out, int out_size, void* d_ws, size_t ws_size,
                              hipStream_t stream) {
    const float* feat = (const float*)d_in[0];
    const int*   flag = (const int*)d_in[1];
    const float* W    = (const float*)d_in[2];
    const float* bias = (const float*)d_in[3];
    float* out = (float*)d_out;

    const long long totalWaves = (long long)B * PAIRS;            // 525312
    const int blocks = (int)((totalWaves + WAVES_PER_BLOCK - 1) / WAVES_PER_BLOCK); // 131328

    contact_map_kernel<<<blocks, 64 * WAVES_PER_BLOCK, 0, stream>>>(feat, flag, W, bias, out);
}

// Round 3
// 91.067 us; speedup vs baseline: 1.9627x; 1.9627x over previous
//
#include <hip/hip_runtime.h>

// Problem constants (from reference setup_inputs)
constexpr int B = 4;
constexpr int L = 512;
constexpr int C = 128;
constexpr int NT = L / 8;                   // 64 tiles per dimension
constexpr int NTILES = NT * (NT + 1) / 2;   // 2080 upper-tri tiles per batch

__device__ __forceinline__ int tri_off(int r) {
    // start of row r in upper-tri (r<=c) enumeration over NT rows
    return r * NT - (r * (r - 1)) / 2;
}

// Block = 256 threads = 4 waves. Each block owns an 8x8 tile of pairs
// (l0..l0+7) x (m0..m0+7), l<=m. Per iteration it=0..7: row i=it of the tile;
// wave w covers tile cols j=2w,2w+1 (one per 32-lane half).
//  - upper rows (l, m0+2w) and (l, m0+2w+1) are contiguous 1024B -> one
//    dwordx4 load across the full wave (lane*16B).
//  - lower row (m0+j, l) is 512B per half; across the 8 iterations each half
//    sweeps a contiguous 4KiB span (l0..l0+7).
//  - if both flags for a pair are 0, the feature loads are skipped entirely.
__global__ __launch_bounds__(256) void cmg_kernel(
    const float* __restrict__ feat,   // [B,L,L,C]
    const int*   __restrict__ flag,   // [B,L,L]
    const float* __restrict__ W,      // [C,2]
    const float* __restrict__ bias,   // [2]
    float*       __restrict__ out)    // [B,L,L,2]
{
    const int tid  = threadIdx.x;
    const int lane = tid & 63;
    const int w    = tid >> 6;       // wave 0..3
    const int h    = lane >> 5;      // half 0..1
    const int sl   = lane & 31;      // sub-lane 0..31

    // ---- decode batch + triangular tile (tl, tm), tl <= tm ----
    const int bid = blockIdx.x;
    const int b   = bid / NTILES;
    const int t   = bid - b * NTILES;
    const float disc = (float)((2 * NT + 1) * (2 * NT + 1)) - 8.0f * (float)t;
    int tl = (int)(((float)(2 * NT + 1) - sqrtf(disc)) * 0.5f);
    tl = min(max(tl, 0), NT - 1);
    while (tl + 1 <= NT - 1 && tri_off(tl + 1) <= t) ++tl;
    while (tri_off(tl) > t) --tl;
    const int tm = tl + (t - tri_off(tl));
    const int l0 = tl * 8, m0 = tm * 8;
    const bool diag = (tl == tm);

    const int j = 2 * w + h;         // tile col for this half (fixed)
    const int m = m0 + j;

    // hoisted per-lane W fragment: channels sl*4 .. sl*4+3, O=2 each
    const float4 w0 = *(const float4*)(W + sl * 8);      // ch 4sl,4sl+1
    const float4 w1 = *(const float4*)(W + sl * 8 + 4);  // ch 4sl+2,4sl+3
    const float b0 = bias[0], b1 = bias[1];

    #pragma unroll
    for (int it = 0; it < 8; ++it) {
        const int l = l0 + it;
        const bool active = !diag || (it <= j);   // skip lower-tri cells of diagonal tiles

        const size_t idxLM = ((size_t)b * L + l) * L + m;
        const size_t idxML = ((size_t)b * L + m) * L + l;

        // flags: half-uniform addresses -> one L1 request per half per load
        int fLM = 0, fML = 0;
        if (active) { fLM = flag[idxLM]; fML = flag[idxML]; }
        const bool doLoad = active && ((fLM | fML) != 0);

        float s0 = 0.f, s1 = 0.f;
        if (doLoad) {
            // upper: both halves' rows, contiguous across the wave
            const float* baseU = feat + (((size_t)b * L + l) * L + (m0 + 2 * w)) * C;
            const float4 u = *(const float4*)(baseU + lane * 4);
            // lower: this half's row (m, l)
            const float* baseL = feat + (((size_t)b * L + m) * L + l) * C;
            const float4 v4 = *(const float4*)(baseL + sl * 4);

            const float x0 = 0.5f * (fmaxf(u.x, 0.f) + fmaxf(v4.x, 0.f));
            const float x1 = 0.5f * (fmaxf(u.y, 0.f) + fmaxf(v4.y, 0.f));
            const float x2 = 0.5f * (fmaxf(u.z, 0.f) + fmaxf(v4.z, 0.f));
            const float x3 = 0.5f * (fmaxf(u.w, 0.f) + fmaxf(v4.w, 0.f));

            s0 = x0 * w0.x + x1 * w0.z + x2 * w1.x + x3 * w1.z;
            s1 = x0 * w0.y + x1 * w0.w + x2 * w1.y + x3 * w1.w;
        }

        // reduce s0 AND s1 over the 32-lane half.
        // Stage 1 CONVERGENT: both shuffles executed by all lanes, then a pure
        // register select (divergent shfl here was round-2's correctness bug —
        // ds_bpermute from exec-masked-off lanes is undefined).
        const float t0 = s0 + __shfl_xor(s0, 1, 64);
        const float t1 = s1 + __shfl_xor(s1, 1, 64);
        float v = (sl & 1) ? t1 : t0;   // even lanes carry s0-pairs, odd s1-pairs
        // Even xor-masks preserve parity; each parity class reduces its own sum.
        v += __shfl_xor(v, 2, 64);
        v += __shfl_xor(v, 4, 64);
        v += __shfl_xor(v, 8, 64);
        v += __shfl_xor(v, 16, 64);
        const float other = __shfl_xor(v, 1, 64);  // writer (even) pulls s1 total

        if (active && sl == 0) {
            const float2 val  = make_float2(v + b0, other + b1);
            const float2 zero = make_float2(0.f, 0.f);
            *(float2*)(out + idxLM * 2) = fLM ? val : zero;
            if (m != l)
                *(float2*)(out + idxML * 2) = fML ? val : zero;
        }
    }
}

extern "C" void kernel_launch(void* const* d_in, const int* in_sizes, int n_in,
                              void* d_out, int out_size, void* d_ws, size_t ws_size,
                              hipStream_t stream) {
    const float* feat = (const float*)d_in[0];
    const int*   flag = (const int*)d_in[1];
    const float* W    = (const float*)d_in[2];
    const float* bias = (const float*)d_in[3];
    float* out = (float*)d_out;

    const int blocks = B * NTILES;   // 8320
    cmg_kernel<<<blocks, 256, 0, stream>>>(feat, flag, W, bias, out);
}

// Round 4
// 87.544 us; speedup vs baseline: 2.0416x; 1.0402x over previous
//
#include <hip/hip_runtime.h>

// Problem constants (from reference setup_inputs)
constexpr int B = 4;
constexpr int L = 512;
constexpr int C = 128;
constexpr int NT = L / 8;                   // 64 tiles per dimension
constexpr int NTILES = NT * (NT + 1) / 2;   // 2080 upper-tri tiles per batch

__device__ __forceinline__ int tri_off(int r) {
    return r * NT - (r * (r - 1)) / 2;
}

// Block = 256 threads = 4 waves; 8x8 pair tile per block (l<=m).
// Three-phase structure so all HBM loads pipeline:
//   A: all 16 flag loads
//   B: all 8 iterations' gated feature loads issued back-to-back (values
//      not consumed -> no waitcnt between branch regions, 16KB in flight)
//   C: 8 independent reduce chains (ILP) + writes
__global__ __launch_bounds__(256) void cmg_kernel(
    const float* __restrict__ feat,   // [B,L,L,C]
    const int*   __restrict__ flag,   // [B,L,L]
    const float* __restrict__ W,      // [C,2]
    const float* __restrict__ bias,   // [2]
    float*       __restrict__ out)    // [B,L,L,2]
{
    const int tid  = threadIdx.x;
    const int lane = tid & 63;
    const int w    = tid >> 6;       // wave 0..3
    const int h    = lane >> 5;      // half 0..1
    const int sl   = lane & 31;      // sub-lane 0..31

    // ---- decode batch + triangular tile (tl, tm), tl <= tm ----
    const int bid = blockIdx.x;
    const int b   = bid / NTILES;
    const int t   = bid - b * NTILES;
    const float disc = (float)((2 * NT + 1) * (2 * NT + 1)) - 8.0f * (float)t;
    int tl = (int)(((float)(2 * NT + 1) - sqrtf(disc)) * 0.5f);
    tl = min(max(tl, 0), NT - 1);
    while (tl + 1 <= NT - 1 && tri_off(tl + 1) <= t) ++tl;
    while (tri_off(tl) > t) --tl;
    const int tm = tl + (t - tri_off(tl));
    const int l0 = tl * 8, m0 = tm * 8;
    const bool diag = (tl == tm);

    const int j = 2 * w + h;         // tile col for this half (fixed)
    const int m = m0 + j;

    // per-lane W fragment: channels 4sl..4sl+3, O=2 each
    const float4 w0 = *(const float4*)(W + sl * 8);
    const float4 w1 = *(const float4*)(W + sl * 8 + 4);
    const float b0 = bias[0], b1 = bias[1];

    // ---- Phase A: flag loads (addresses independent -> all issue at once) ----
    int fLM[8], fML[8];
    #pragma unroll
    for (int it = 0; it < 8; ++it) {
        const int l = l0 + it;
        fLM[it] = flag[((size_t)b * L + l) * L + m];
        fML[it] = flag[((size_t)b * L + m) * L + l];
    }

    // ---- Phase B: gated feature loads, staged in registers ----
    float4 u[8], v4[8];
    #pragma unroll
    for (int it = 0; it < 8; ++it) {
        const int l = l0 + it;
        const bool active = !diag || (it <= j);
        const bool doLoad = active && ((fLM[it] | fML[it]) != 0);
        float4 uu = make_float4(0.f, 0.f, 0.f, 0.f);
        float4 vv = uu;
        if (doLoad) {
            const float* baseU = feat + (((size_t)b * L + l) * L + (m0 + 2 * w)) * C;
            uu = *(const float4*)(baseU + lane * 4);          // upper row, full wave
            const float* baseL = feat + (((size_t)b * L + m) * L + l) * C;
            vv = *(const float4*)(baseL + sl * 4);            // lower row, per half
        }
        u[it] = uu;
        v4[it] = vv;
    }

    // ---- Phase C: reduce + write ----
    #pragma unroll
    for (int it = 0; it < 8; ++it) {
        const int l = l0 + it;
        const bool active = !diag || (it <= j);

        const float x0 = 0.5f * (fmaxf(u[it].x, 0.f) + fmaxf(v4[it].x, 0.f));
        const float x1 = 0.5f * (fmaxf(u[it].y, 0.f) + fmaxf(v4[it].y, 0.f));
        const float x2 = 0.5f * (fmaxf(u[it].z, 0.f) + fmaxf(v4[it].z, 0.f));
        const float x3 = 0.5f * (fmaxf(u[it].w, 0.f) + fmaxf(v4[it].w, 0.f));

        const float s0 = x0 * w0.x + x1 * w0.z + x2 * w1.x + x3 * w1.z;
        const float s1 = x0 * w0.y + x1 * w0.w + x2 * w1.y + x3 * w1.w;

        // convergent parity-trick reduce over the 32-lane half (7 shfls)
        const float t0 = s0 + __shfl_xor(s0, 1, 64);
        const float t1 = s1 + __shfl_xor(s1, 1, 64);
        float v = (sl & 1) ? t1 : t0;
        v += __shfl_xor(v, 2, 64);
        v += __shfl_xor(v, 4, 64);
        v += __shfl_xor(v, 8, 64);
        v += __shfl_xor(v, 16, 64);
        const float other = __shfl_xor(v, 1, 64);

        if (active && sl == 0) {
            const size_t idxLM = ((size_t)b * L + l) * L + m;
            const size_t idxML = ((size_t)b * L + m) * L + l;
            const float2 val  = make_float2(v + b0, other + b1);
            const float2 zero = make_float2(0.f, 0.f);
            *(float2*)(out + idxLM * 2) = fLM[it] ? val : zero;
            if (m != l)
                *(float2*)(out + idxML * 2) = fML[it] ? val : zero;
        }
    }
}

extern "C" void kernel_launch(void* const* d_in, const int* in_sizes, int n_in,
                              void* d_out, int out_size, void* d_ws, size_t ws_size,
                              hipStream_t stream) {
    const float* feat = (const float*)d_in[0];
    const int*   flag = (const int*)d_in[1];
    const float* W    = (const float*)d_in[2];
    const float* bias = (const float*)d_in[3];
    float* out = (float*)d_out;

    const int blocks = B * NTILES;   // 8320
    cmg_kernel<<<blocks, 256, 0, stream>>>(feat, flag, W, bias, out);
}